// Round 2
// baseline (291.895 us; speedup 1.0000x reference)
//
#include <hip/hip_runtime.h>
#include <cmath>

#define D_IN 256
#define H_DIM 128
#define NUM_GRAPHS 1024
#define CHUNK 512
#define SUBT 64
#define NSUBT (CHUNK / SUBT)
#define MAXSEG 16
#define REC_F 768  // floats per record: ewsum[256], ssum[256], mx[256]

typedef __attribute__((ext_vector_type(8))) __bf16 bf16x8;
typedef __attribute__((ext_vector_type(4))) float f32x4;

// ---------------------------------------------------------------------------
// Pack W1 (f32 [256][128]) into bf16 MFMA B-fragment order.
// B-frag for mfma_f32_16x16x32_bf16: lane l holds B[k][n], n = nt*16 + (l&15),
// k = ks*32 + (l>>4)*8 + i. packed[((nt*8+ks)*64 + l)*8 + i]
// ---------------------------------------------------------------------------
__global__ void pack_w1(const float* __restrict__ W1, ushort* __restrict__ packed) {
    int tid = blockIdx.x * 256 + threadIdx.x;
    if (tid >= 8 * 8 * 64) return;
    int nt = tid >> 9;
    int ks = (tid >> 6) & 7;
    int l = tid & 63;
    int col = nt * 16 + (l & 15);
    int kbase = ks * 32 + ((l >> 4) & 3) * 8;
#pragma unroll
    for (int i = 0; i < 8; ++i) {
        float v = W1[(size_t)(kbase + i) * H_DIM + col];
        __bf16 b = (__bf16)v;
        packed[(size_t)tid * 8 + i] = *reinterpret_cast<ushort*>(&b);
    }
}

// ---------------------------------------------------------------------------
// Fused: scores (MFMA) + unnormalized-softmax pooling partials, one x read.
// Block = 256 threads (4 waves), chunk of 512 sorted nodes, 64-node sub-tiles.
// ---------------------------------------------------------------------------
__global__ __launch_bounds__(256) void fused_kernel(
    const float* __restrict__ x, const ushort* __restrict__ w1p,
    const float* __restrict__ b1, const float* __restrict__ W2,
    const float* __restrict__ b2, const int* __restrict__ batch,
    float* __restrict__ recs, int2* __restrict__ hdr,
    float* __restrict__ zpart, int N) {
    int tid = threadIdx.x;
    int l = tid & 63;
    int w = tid >> 6;
    int r = l & 15;
    int kg = l >> 4;
    int blk = blockIdx.x;
    long long base = (long long)blk * CHUNK;
    int chunkN = (int)min((long long)CHUNK, (long long)N - base);

    __shared__ float escore[SUBT];
    __shared__ int sbatch[CHUNK];
    __shared__ int seglist[MAXSEG + 1];
    __shared__ int snseg;
    __shared__ f32x4 red[256];

    if (tid < MAXSEG) hdr[blk * MAXSEG + tid] = make_int2(-1, 0);

    for (int i = tid; i < chunkN; i += 256) sbatch[i] = batch[base + i];
    __syncthreads();

    // segment boundary scan (wave 0, ballot-compaction)
    if (tid < 64) {
        int nseg = 0;
        for (int t0 = 0; t0 < chunkN; t0 += 64) {
            int i = t0 + l;
            bool flag = (i < chunkN) && (i == 0 || sbatch[i] != sbatch[i - 1]);
            unsigned long long m = __ballot(flag);
            if (l == 0) {
                while (m) {
                    int b = __ffsll((unsigned long long)m) - 1;
                    if (nseg < MAXSEG) seglist[nseg] = t0 + b;
                    nseg++;
                    m &= m - 1;
                }
            }
            nseg = __shfl(nseg, 0, 64);
        }
        if (l == 0) {
            if (nseg > MAXSEG) nseg = MAXSEG;
            snseg = nseg;
            seglist[nseg] = chunkN;
        }
    }
    __syncthreads();

    // hoisted epilogue weights
    float w2v[8], b1v[8];
#pragma unroll
    for (int nt = 0; nt < 8; ++nt) {
        int c = nt * 16 + r;
        w2v[nt] = W2[c];
        b1v[nt] = b1[c];
    }
    float bb = b2[0];

    int cg = tid >> 6;
    int c0 = (tid & 63) * 4;

    f32x4 asum = {0.f, 0.f, 0.f, 0.f};
    f32x4 ssum = {0.f, 0.f, 0.f, 0.f};
    f32x4 mx = {-INFINITY, -INFINITY, -INFINITY, -INFINITY};
    float zacc = 0.f;
    int curseg = 0;
    int nsegL = snseg;

    for (int t = 0; t < NSUBT; ++t) {
        if (t * SUBT >= chunkN) break;  // uniform

        // ---- scores for 64 rows via MFMA ----
        long long rowBase = base + t * SUBT + w * 16;
        long long arow = rowBase + r;
        if (arow >= N) arow = N - 1;
        const float* xptr = x + arow * D_IN + kg * 8;
        f32x4 acc[8] = {};
#pragma unroll
        for (int ks = 0; ks < 8; ++ks) {
            f32x4 a0 = *(const f32x4*)(xptr + ks * 32);
            f32x4 a1 = *(const f32x4*)(xptr + ks * 32 + 4);
            bf16x8 af;
#pragma unroll
            for (int i = 0; i < 4; ++i) {
                af[i] = (__bf16)a0[i];
                af[i + 4] = (__bf16)a1[i];
            }
#pragma unroll
            for (int nt = 0; nt < 8; ++nt) {
                bf16x8 bf = *(const bf16x8*)(w1p + ((size_t)(nt * 8 + ks) * 64 + l) * 8);
                acc[nt] = __builtin_amdgcn_mfma_f32_16x16x32_bf16(af, bf, acc[nt], 0, 0, 0);
            }
        }
#pragma unroll
        for (int reg = 0; reg < 4; ++reg) {
            float p = 0.f;
#pragma unroll
            for (int nt = 0; nt < 8; ++nt) {
                float h = acc[nt][reg] + b1v[nt];
                p += fmaxf(h, 0.f) * w2v[nt];
            }
            p += __shfl_xor(p, 1, 64);
            p += __shfl_xor(p, 2, 64);
            p += __shfl_xor(p, 4, 64);
            p += __shfl_xor(p, 8, 64);
            long long row = rowBase + kg * 4 + reg;
            if (r == 0) {
                int li = w * 16 + kg * 4 + reg;
                escore[li] = (row < N) ? __expf(p + bb) : 0.f;
            }
        }
        __syncthreads();

        if (tid < SUBT) zacc += escore[tid];

        // ---- pool this sub-tile (x re-read is L2-hot) ----
        int tlo = t * SUBT, thi = min(t * SUBT + SUBT, chunkN);
        while (tlo < thi) {
            int s1 = seglist[curseg + 1];
            int hi = min(s1, thi);
            for (int i = tlo + cg; i < hi; i += 4) {
                f32x4 v = *(const f32x4*)(x + (base + i) * D_IN + c0);
                float wgt = escore[i & (SUBT - 1)];
#pragma unroll
                for (int j = 0; j < 4; ++j) {
                    asum[j] += v[j] * wgt;
                    ssum[j] += v[j];
                    mx[j] = fmaxf(mx[j], v[j]);
                }
            }
            if (hi == s1 && curseg < nsegL) {
                // flush segment partial (uniform condition)
                float* rb = recs + (size_t)(blk * MAXSEG + curseg) * REC_F;
                red[tid] = asum;
                __syncthreads();
                if (cg == 0) {
                    f32x4 a = red[tid];
#pragma unroll
                    for (int k = 1; k < 4; ++k) {
                        f32x4 o = red[tid + 64 * k];
#pragma unroll
                        for (int j = 0; j < 4; ++j) a[j] += o[j];
                    }
                    *(f32x4*)(rb + c0) = a;
                }
                __syncthreads();
                red[tid] = ssum;
                __syncthreads();
                if (cg == 0) {
                    f32x4 a = red[tid];
#pragma unroll
                    for (int k = 1; k < 4; ++k) {
                        f32x4 o = red[tid + 64 * k];
#pragma unroll
                        for (int j = 0; j < 4; ++j) a[j] += o[j];
                    }
                    *(f32x4*)(rb + 256 + c0) = a;
                }
                __syncthreads();
                red[tid] = mx;
                __syncthreads();
                if (cg == 0) {
                    f32x4 a = red[tid];
#pragma unroll
                    for (int k = 1; k < 4; ++k) {
                        f32x4 o = red[tid + 64 * k];
#pragma unroll
                        for (int j = 0; j < 4; ++j) a[j] = fmaxf(a[j], o[j]);
                    }
                    *(f32x4*)(rb + 512 + c0) = a;
                }
                if (tid == 0)
                    hdr[blk * MAXSEG + curseg] =
                        make_int2(sbatch[seglist[curseg]], s1 - seglist[curseg]);
                __syncthreads();
#pragma unroll
                for (int j = 0; j < 4; ++j) {
                    asum[j] = 0.f;
                    ssum[j] = 0.f;
                    mx[j] = -INFINITY;
                }
                curseg++;
            }
            tlo = hi;
        }
        __syncthreads();  // escore reused next sub-tile
    }

    // block z partial
    if (tid < 64) {
        zacc += __shfl_xor(zacc, 32, 64);
        zacc += __shfl_xor(zacc, 16, 64);
        zacc += __shfl_xor(zacc, 8, 64);
        zacc += __shfl_xor(zacc, 4, 64);
        zacc += __shfl_xor(zacc, 2, 64);
        zacc += __shfl_xor(zacc, 1, 64);
        if (l == 0) zpart[blk] = zacc;
    }
}

// ---------------------------------------------------------------------------
__device__ inline int lower_bound_i(const int* __restrict__ arr, int n, int val) {
    int lo = 0, hi = n;
    while (lo < hi) {
        int mid = (lo + hi) >> 1;
        if (arr[mid] < val) lo = mid + 1; else hi = mid;
    }
    return lo;
}

// One block per graph: merge partial records, normalize by Z, write output.
__global__ __launch_bounds__(256) void combine_kernel(
    const float* __restrict__ recs, const int2* __restrict__ hdr,
    const float* __restrict__ zpart, int nblk,
    const int* __restrict__ batch, int N, float* __restrict__ out) {
    int g = blockIdx.x;
    int tid = threadIdx.x;

    __shared__ float szr[256];
    float zs = 0.f;
    for (int i = tid; i < nblk; i += 256) zs += zpart[i];
    szr[tid] = zs;
    __syncthreads();
    for (int off = 128; off > 0; off >>= 1) {
        if (tid < off) szr[tid] += szr[tid + off];
        __syncthreads();
    }
    float invZ = 1.f / szr[0];

    __shared__ int sb[2];
    if (tid < 2) sb[tid] = lower_bound_i(batch, N, g + tid);
    __syncthreads();
    int start = sb[0], end = sb[1];

    float ew = 0.f, ss = 0.f, mxv = -INFINITY;
    int cnt = 0;
    if (end > start) {
        int b0 = start / CHUNK, b1 = (end - 1) / CHUNK;
        for (int b = b0; b <= b1; ++b) {
            for (int si = 0; si < MAXSEG; ++si) {
                int2 h = hdr[b * MAXSEG + si];
                if (h.x == g) {
                    const float* rb = recs + (size_t)(b * MAXSEG + si) * REC_F;
                    ew += rb[tid];
                    ss += rb[256 + tid];
                    mxv = fmaxf(mxv, rb[512 + tid]);
                    cnt += h.y;
                }
            }
        }
    }
    size_t ob = (size_t)g * (3 * D_IN);
    out[ob + tid] = ew * invZ;
    out[ob + D_IN + tid] = (cnt > 0) ? mxv : 0.f;
    out[ob + 2 * D_IN + tid] = ss / (float)max(cnt, 1);
}

// ---------------------------------------------------------------------------
extern "C" void kernel_launch(void* const* d_in, const int* in_sizes, int n_in,
                              void* d_out, int out_size, void* d_ws, size_t ws_size,
                              hipStream_t stream) {
    const float* x = (const float*)d_in[0];
    const float* W1 = (const float*)d_in[1];
    const float* b1 = (const float*)d_in[2];
    const float* W2 = (const float*)d_in[3];
    const float* b2 = (const float*)d_in[4];
    const int* batch = (const int*)d_in[5];
    int N = in_sizes[0] / D_IN;
    float* out = (float*)d_out;
    int NB = (N + CHUNK - 1) / CHUNK;

    char* ws = (char*)d_ws;
    size_t off = 0;
    ushort* w1p = (ushort*)(ws + off);
    off += 8 * 8 * 64 * 8 * sizeof(ushort);          // 64 KB
    off = (off + 255) & ~(size_t)255;
    float* recs = (float*)(ws + off);
    off += (size_t)NB * MAXSEG * REC_F * sizeof(float);  // ~48 MB
    off = (off + 255) & ~(size_t)255;
    int2* hdr = (int2*)(ws + off);
    off += (size_t)NB * MAXSEG * sizeof(int2);
    off = (off + 255) & ~(size_t)255;
    float* zpart = (float*)(ws + off);
    off += (size_t)NB * sizeof(float);

    pack_w1<<<16, 256, 0, stream>>>(W1, w1p);
    fused_kernel<<<NB, 256, 0, stream>>>(x, w1p, b1, W2, b2, batch,
                                         recs, hdr, zpart, N);
    combine_kernel<<<NUM_GRAPHS, 256, 0, stream>>>(recs, hdr, zpart, NB,
                                                   batch, N, out);
}